// Round 3
// baseline (230.869 us; speedup 1.0000x reference)
//
#include <hip/hip_runtime.h>
#include <hip/hip_bf16.h>
#include <stdint.h>

typedef __bf16 bf16_t;
typedef __attribute__((ext_vector_type(8))) __bf16 bf16x8;
typedef __attribute__((ext_vector_type(4))) float f32x4;

// ---------------------------------------------------------------------------
// q8: exact re-implementation of reference to_float8.
// ---------------------------------------------------------------------------
__device__ __forceinline__ float q8(float v) {
    float a = __builtin_fabsf(v);
    float z = a + 1e-8f;
    int ei = ((__float_as_int(z) >> 23) & 0xff) - 127;
    ei = ei > 7 ? 7 : (ei < -7 ? -7 : ei);
    float p  = __int_as_float((ei + 127) << 23);
    float ip = __int_as_float((127 - ei) << 23);
    float m  = __builtin_fmaf(a, ip, -1.0f);
    float mq = __builtin_rintf(m * 8.0f) * 0.125f;
    float r  = (1.0f + mq) * p;
    return v < 0.0f ? -r : r;
}

__device__ __forceinline__ void gload_lds16(const bf16_t* g, bf16_t* l) {
    __builtin_amdgcn_global_load_lds(
        (__attribute__((address_space(1))) void*)(g),
        (__attribute__((address_space(3))) void*)(l), 16, 0, 0);
}

template<int N> __device__ __forceinline__ void vmwait() {
    if constexpr (N == 0)      asm volatile("s_waitcnt vmcnt(0)" ::: "memory");
    else if constexpr (N == 5) asm volatile("s_waitcnt vmcnt(5)" ::: "memory");
    else if constexpr (N == 6) asm volatile("s_waitcnt vmcnt(6)" ::: "memory");
}

__device__ __forceinline__ bf16x8 cvt8(float4 a, float4 b) {
    bf16x8 o = { (bf16_t)a.x, (bf16_t)a.y, (bf16_t)a.z, (bf16_t)a.w,
                 (bf16_t)b.x, (bf16_t)b.y, (bf16_t)b.z, (bf16_t)b.w };
    return o;
}
__device__ __forceinline__ bf16x8 q8x8(float4 a, float4 b) {
    bf16x8 o = { (bf16_t)q8(a.x), (bf16_t)q8(a.y), (bf16_t)q8(a.z), (bf16_t)q8(a.w),
                 (bf16_t)q8(b.x), (bf16_t)q8(b.y), (bf16_t)q8(b.z), (bf16_t)q8(b.w) };
    return o;
}

// ---------------------------------------------------------------------------
// Fused pack kernel, 10240 blocks x 256 threads, 8 elems/thread, 16B stores.
// ---------------------------------------------------------------------------
__global__ void pack_all(const float* __restrict__ x, const float* __restrict__ u,
                         const float* __restrict__ A, const float* __restrict__ B,
                         const float* __restrict__ C,
                         bf16_t* __restrict__ XU, bf16_t* __restrict__ AB,
                         bf16_t* __restrict__ CQ) {
    const unsigned bid = blockIdx.x;
    const int tid = threadIdx.x;
    if (bid < 4096u) {
        size_t r = bid; int col = tid * 8;
        float4 v0 = *(const float4*)&x[r * 2048 + col];
        float4 v1 = *(const float4*)&x[r * 2048 + col + 4];
        *(bf16x8*)&XU[r * 3072 + col] = cvt8(v0, v1);
    } else if (bid < 6144u) {
        unsigned b = bid - 4096u;
        size_t r = b * 2 + (tid >> 7); int col = (tid & 127) * 8;
        float4 v0 = *(const float4*)&u[r * 1024 + col];
        float4 v1 = *(const float4*)&u[r * 1024 + col + 4];
        *(bf16x8*)&XU[r * 3072 + 2048 + col] = cvt8(v0, v1);
    } else if (bid < 8192u) {
        size_t r = bid - 6144u; int col = tid * 8;
        float4 v0 = *(const float4*)&A[r * 2048 + col];
        float4 v1 = *(const float4*)&A[r * 2048 + col + 4];
        *(bf16x8*)&AB[r * 3072 + col] = q8x8(v0, v1);
    } else if (bid < 9216u) {
        unsigned b = bid - 8192u;
        size_t r = b * 2 + (tid >> 7); int col = (tid & 127) * 8;
        float4 v0 = *(const float4*)&B[r * 1024 + col];
        float4 v1 = *(const float4*)&B[r * 1024 + col + 4];
        *(bf16x8*)&AB[r * 3072 + 2048 + col] = q8x8(v0, v1);
    } else {
        size_t r = bid - 9216u; int col = tid * 8;
        float4 v0 = *(const float4*)&C[r * 2048 + col];
        float4 v1 = *(const float4*)&C[r * 2048 + col + 4];
        *(bf16x8*)&CQ[r * 2048 + col] = q8x8(v0, v1);
    }
}

// ---------------------------------------------------------------------------
// GEMM (B^T): outf[i,j] = q8( sum_k A[i,k]*B[j,k] ), f32 out, optional bf16.
// Round-10: triple-buffered ring, ONE barrier + ONE counted vmcnt per K-tile.
//  * BM=256, BN=128/64, BK=64, 512 thr = 8 waves (4M x 2N), wave 64 x BN/2.
//    Grid 16x16 = 256 blocks for BOTH gemms (fixes gemm2's 309-TF structure).
//  * LDS ring of 3 (A 32KB + B 16/8KB) buffers = 144/120 KB, 1 block/CU.
//  * Per K-tile t: [issue stage(t+2) -> buf[(t+2)%3]] ; substep0 {4+NI
//    ds_read_b128, setprio1, 16/8 MFMA, setprio0} ; substep1 {same} ;
//    vmcnt(TOT) ; s_barrier.  32/16 MFMA per barrier (vs R2's 8 per 2
//    barriers -- the measured regression driver), loads never drained:
//    vmcnt(TOT) retires stage(t+1) (issued a FULL K-tile ago, ~320+ cy of
//    compute cover) while stage(t+2)'s TOT loads stay in flight.
//  * WAR ledger: stage(t+2) targets buf[(t-1)%3]; every wave's ds_reads of
//    that buffer retired (compiler lgkm before MFMA use) before the tile-end
//    barrier of t-1; stage(t+2) issues after that barrier. Publish ledger:
//    vmcnt(TOT) retires own stage(t+1) loads, barrier aligns all waves, so
//    tile t+1's reads see complete data. Edges: t+2>=NT -> nothing staged,
//    vmcnt(0) (exact drain of the last pending stage).
//  * Addressing/swizzle byte-identical to the verified-passing R1/R2 pattern:
//    LDS lane-linear (gload_lds requirement), global chunk c^(r&7), ds_read
//    applies same XOR. Bank conflicts measured 0 with this pattern.
//  * K-accumulation order (ascending 32-chunks) identical -> bit-identical.
// ---------------------------------------------------------------------------
template<int BN, bool DUAL>
__global__ __launch_bounds__(512, 2)
void gemm_q8_r3(const bf16_t* __restrict__ Ap, const bf16_t* __restrict__ Bp,
                float* __restrict__ outf, bf16_t* __restrict__ outb,
                int N, int K) {
    constexpr int BM = 256;
    constexpr int BK = 64;
    constexpr int NI    = BN / 32;       // B frags per substep: 4 or 2
    constexpr int B_ITS = BN / 64;       // B stage loads/thread: 2 or 1
    constexpr int TOT   = 4 + B_ITS;     // stage loads/thread/tile: 6 or 5
    constexpr int ABUF  = BM * BK;       // 16384 elems = 32 KB
    constexpr int BBUF  = BN * BK;       // 8192 / 4096 elems

    __shared__ alignas(16) bf16_t sA[3][ABUF];
    __shared__ alignas(16) bf16_t sB[3][BBUF];

    const int tid  = threadIdx.x;
    const int lane = tid & 63;
    const int wave = tid >> 6;       // 0..7
    const int wm   = wave & 3;       // 4 m-strips of 64 rows
    const int wn   = wave >> 2;      // 2 n-strips of BN/2 cols
    const int ln16 = lane & 15;
    const int quad = lane >> 4;

    // XCD patch swizzle on the 16x16 block grid: xcd=b&7 owns an 8x4 patch
    const int b   = blockIdx.x;
    const int xcd = b & 7;
    const int g   = b >> 3;                          // 0..31
    const int bx  = (xcd & 1) * 8 + (g & 7);         // 0..15
    const int by  = (xcd >> 1) * 4 + (g >> 3);       // 0..15
    const int brow = by * BM;
    const int bcol = bx * BN;

    // ---- staging pointers (proven pattern: LDS lane-linear, src chunk XOR) --
    const bf16_t* gA[4];
#pragma unroll
    for (int it = 0; it < 4; ++it) {
        int L = it * 512 + tid;
        int r = L >> 3, c = L & 7;
        gA[it] = Ap + (size_t)(brow + r) * K + (c ^ (r & 7)) * 8;
    }
    const bf16_t* gB[B_ITS];
#pragma unroll
    for (int it = 0; it < B_ITS; ++it) {
        int L = it * 512 + tid;
        int r = L >> 3, c = L & 7;
        gB[it] = Bp + (size_t)(bcol + r) * K + (c ^ (r & 7)) * 8;
    }

    // ---- fragment LDS offsets (elements), s = K-substep (0..1) ----
    int a_off[4][2], b_off[NI][2];
#pragma unroll
    for (int im = 0; im < 4; ++im) {
        int r = wm * 64 + im * 16 + ln16;
#pragma unroll
        for (int s = 0; s < 2; ++s) {
            int cg = s * 4 + quad;
            a_off[im][s] = (r * 8 + (cg ^ (r & 7))) * 8;
        }
    }
#pragma unroll
    for (int in = 0; in < NI; ++in) {
        int r = wn * (BN / 2) + in * 16 + ln16;
#pragma unroll
        for (int s = 0; s < 2; ++s) {
            int cg = s * 4 + quad;
            b_off[in][s] = (r * 8 + (cg ^ (r & 7))) * 8;
        }
    }

    f32x4 acc[4][NI];
#pragma unroll
    for (int im = 0; im < 4; ++im)
#pragma unroll
        for (int in = 0; in < NI; ++in)
            acc[im][in] = (f32x4){0.f, 0.f, 0.f, 0.f};

    auto STAGE = [&](int sb) {
#pragma unroll
        for (int it = 0; it < 4; ++it) {
            gload_lds16(gA[it], &sA[sb][(it * 512 + wave * 64) * 8]);
            gA[it] += BK;
        }
#pragma unroll
        for (int it = 0; it < B_ITS; ++it) {
            gload_lds16(gB[it], &sB[sb][(it * 512 + wave * 64) * 8]);
            gB[it] += BK;
        }
    };

    // ---- prologue: fill buf0, buf1; publish buf0 (stage(1) stays in flight)
    STAGE(0);
    STAGE(1);
    vmwait<TOT>();                       // retire stage(0); stage(1) in flight
    __builtin_amdgcn_s_barrier();
    asm volatile("" ::: "memory");

    const int NT = K / BK;
    int rb = 0;                          // ring index = t % 3
    for (int t = 0; t < NT; ++t) {
        // issue next-next tile's stage into the buffer freed at barrier(t-1)
        if (t + 2 < NT) {
            int sb = rb + 2; if (sb >= 3) sb -= 3;
            STAGE(sb);
        }
        const bf16_t* bA = sA[rb];
        const bf16_t* bB = sB[rb];
        // -------- substep 0 (k 0..31)
        {
            bf16x8 af[4], bfv[NI];
#pragma unroll
            for (int im = 0; im < 4; ++im) af[im]  = *(const bf16x8*)(bA + a_off[im][0]);
#pragma unroll
            for (int in = 0; in < NI; ++in) bfv[in] = *(const bf16x8*)(bB + b_off[in][0]);
            __builtin_amdgcn_s_setprio(1);
#pragma unroll
            for (int im = 0; im < 4; ++im)
#pragma unroll
                for (int in = 0; in < NI; ++in)
                    acc[im][in] = __builtin_amdgcn_mfma_f32_16x16x32_bf16(
                        af[im], bfv[in], acc[im][in], 0, 0, 0);
            __builtin_amdgcn_s_setprio(0);
        }
        // -------- substep 1 (k 32..63)
        {
            bf16x8 af[4], bfv[NI];
#pragma unroll
            for (int im = 0; im < 4; ++im) af[im]  = *(const bf16x8*)(bA + a_off[im][1]);
#pragma unroll
            for (int in = 0; in < NI; ++in) bfv[in] = *(const bf16x8*)(bB + b_off[in][1]);
            __builtin_amdgcn_s_setprio(1);
#pragma unroll
            for (int im = 0; im < 4; ++im)
#pragma unroll
                for (int in = 0; in < NI; ++in)
                    acc[im][in] = __builtin_amdgcn_mfma_f32_16x16x32_bf16(
                        af[im], bfv[in], acc[im][in], 0, 0, 0);
            __builtin_amdgcn_s_setprio(0);
        }
        // publish stage(t+1) (retire it; stage(t+2) stays in flight)
        if (t + 2 < NT) vmwait<TOT>(); else vmwait<0>();
        __builtin_amdgcn_s_barrier();
        asm volatile("" ::: "memory");
        rb = rb + 1; if (rb == 3) rb = 0;
    }

    // ---- epilogue: C/D layout col = lane&15, row = quad*4 + reg
    const int rbase = quad * 4;
#pragma unroll
    for (int im = 0; im < 4; ++im) {
#pragma unroll
        for (int in = 0; in < NI; ++in) {
            int gm = brow + wm * 64 + im * 16 + rbase;
            int gn = bcol + wn * (BN / 2) + in * 16 + ln16;
#pragma unroll
            for (int r = 0; r < 4; ++r) {
                float v = q8(acc[im][in][r]);
                outf[(size_t)(gm + r) * N + gn] = v;
                if (DUAL) outb[(size_t)(gm + r) * N + gn] = (bf16_t)v;
            }
        }
    }
}

// ---------------------------------------------------------------------------
extern "C" void kernel_launch(void* const* d_in, const int* in_sizes, int n_in,
                              void* d_out, int out_size, void* d_ws, size_t ws_size,
                              hipStream_t stream) {
    const float* x = (const float*)d_in[0];   // 4096 x 2048
    const float* u = (const float*)d_in[1];   // 4096 x 1024
    const float* A = (const float*)d_in[2];   // 2048 x 2048
    const float* B = (const float*)d_in[3];   // 2048 x 1024
    const float* C = (const float*)d_in[4];   // 1024 x 2048

    float* outf = (float*)d_out;
    float* xnf  = outf;                                 // 4096 x 2048 f32
    float* yf   = outf + (size_t)4096 * 2048;           // 4096 x 1024 f32

    uint8_t* ws = (uint8_t*)d_ws;
    bf16_t* XU = (bf16_t*)ws;                                            // 24 MB
    bf16_t* AB = (bf16_t*)(ws + (size_t)25165824);                       // 12 MB
    bf16_t* CQ = (bf16_t*)(ws + (size_t)25165824 + 12582912);            //  4 MB
    bf16_t* XN = (bf16_t*)(ws + (size_t)25165824 + 12582912 + 4194304);  // 16 MB

    pack_all<<<dim3(10240), 256, 0, stream>>>(x, u, A, B, C, XU, AB, CQ);

    // x_next = q8([x|u] @ [Aq|Bq]^T): M=4096 N=2048 K=3072; grid 16x16
    gemm_q8_r3<128, true><<<dim3(256), 512, 0, stream>>>(
        XU, AB, xnf, XN, 2048, 3072);
    // y = q8(x_next @ Cq^T): M=4096 N=1024 K=2048; grid 16x16
    gemm_q8_r3<64, false><<<dim3(256), 512, 0, stream>>>(
        XN, CQ, yf, nullptr, 1024, 2048);
}

// Round 5
// 200.951 us; speedup vs baseline: 1.1489x; 1.1489x over previous
//
#include <hip/hip_runtime.h>
#include <hip/hip_bf16.h>
#include <stdint.h>

typedef __bf16 bf16_t;
typedef __attribute__((ext_vector_type(8))) __bf16 bf16x8;
typedef __attribute__((ext_vector_type(4))) __bf16 bf16x4;
typedef __attribute__((ext_vector_type(4))) float f32x4;

// ---------------------------------------------------------------------------
// q8: exact re-implementation of reference to_float8.
// ---------------------------------------------------------------------------
__device__ __forceinline__ float q8(float v) {
    float a = __builtin_fabsf(v);
    float z = a + 1e-8f;
    int ei = ((__float_as_int(z) >> 23) & 0xff) - 127;
    ei = ei > 7 ? 7 : (ei < -7 ? -7 : ei);
    float p  = __int_as_float((ei + 127) << 23);
    float ip = __int_as_float((127 - ei) << 23);
    float m  = __builtin_fmaf(a, ip, -1.0f);
    float mq = __builtin_rintf(m * 8.0f) * 0.125f;
    float r  = (1.0f + mq) * p;
    return v < 0.0f ? -r : r;
}

__device__ __forceinline__ void gload_lds16(const bf16_t* g, bf16_t* l) {
    __builtin_amdgcn_global_load_lds(
        (__attribute__((address_space(1))) void*)(g),
        (__attribute__((address_space(3))) void*)(l), 16, 0, 0);
}

__device__ __forceinline__ bf16x8 cvt8(float4 a, float4 b) {
    bf16x8 o = { (bf16_t)a.x, (bf16_t)a.y, (bf16_t)a.z, (bf16_t)a.w,
                 (bf16_t)b.x, (bf16_t)b.y, (bf16_t)b.z, (bf16_t)b.w };
    return o;
}
__device__ __forceinline__ bf16x8 q8x8(float4 a, float4 b) {
    bf16x8 o = { (bf16_t)q8(a.x), (bf16_t)q8(a.y), (bf16_t)q8(a.z), (bf16_t)q8(a.w),
                 (bf16_t)q8(b.x), (bf16_t)q8(b.y), (bf16_t)q8(b.z), (bf16_t)q8(b.w) };
    return o;
}

// ---------------------------------------------------------------------------
// Fused pack kernel, 10240 blocks x 256 threads, 8 elems/thread, 16B stores.
// (verified passing R1-R3; kept as the only orthogonal improvement)
//   [0,4096):      x rows   -> XU[:, 0:2048]      (bf16 cast)
//   [4096,6144):   u rows   -> XU[:, 2048:3072]   (2 rows/block)
//   [6144,8192):   A rows   -> AB[:, 0:2048]      (q8)
//   [8192,9216):   B rows   -> AB[:, 2048:3072]   (q8, 2 rows/block)
//   [9216,10240):  C rows   -> CQ                 (q8)
// ---------------------------------------------------------------------------
__global__ void pack_all(const float* __restrict__ x, const float* __restrict__ u,
                         const float* __restrict__ A, const float* __restrict__ B,
                         const float* __restrict__ C,
                         bf16_t* __restrict__ XU, bf16_t* __restrict__ AB,
                         bf16_t* __restrict__ CQ) {
    const unsigned bid = blockIdx.x;
    const int tid = threadIdx.x;
    if (bid < 4096u) {
        size_t r = bid; int col = tid * 8;
        float4 v0 = *(const float4*)&x[r * 2048 + col];
        float4 v1 = *(const float4*)&x[r * 2048 + col + 4];
        *(bf16x8*)&XU[r * 3072 + col] = cvt8(v0, v1);
    } else if (bid < 6144u) {
        unsigned b = bid - 4096u;
        size_t r = b * 2 + (tid >> 7); int col = (tid & 127) * 8;
        float4 v0 = *(const float4*)&u[r * 1024 + col];
        float4 v1 = *(const float4*)&u[r * 1024 + col + 4];
        *(bf16x8*)&XU[r * 3072 + 2048 + col] = cvt8(v0, v1);
    } else if (bid < 8192u) {
        size_t r = bid - 6144u; int col = tid * 8;
        float4 v0 = *(const float4*)&A[r * 2048 + col];
        float4 v1 = *(const float4*)&A[r * 2048 + col + 4];
        *(bf16x8*)&AB[r * 3072 + col] = q8x8(v0, v1);
    } else if (bid < 9216u) {
        unsigned b = bid - 8192u;
        size_t r = b * 2 + (tid >> 7); int col = (tid & 127) * 8;
        float4 v0 = *(const float4*)&B[r * 1024 + col];
        float4 v1 = *(const float4*)&B[r * 1024 + col + 4];
        *(bf16x8*)&AB[r * 3072 + 2048 + col] = q8x8(v0, v1);
    } else {
        size_t r = bid - 9216u; int col = tid * 8;
        float4 v0 = *(const float4*)&C[r * 2048 + col];
        float4 v1 = *(const float4*)&C[r * 2048 + col + 4];
        *(bf16x8*)&CQ[r * 2048 + col] = q8x8(v0, v1);
    }
}

// ---------------------------------------------------------------------------
// GEMM (B^T): outf[i,j] = q8( sum_k A[i,k]*B[j,k] ), f32 out, optional bf16
// copy. EXACT round-0 verified config (56.9 us gemm1, 905 TF, MfmaUtil 36%,
// conflicts 0, 2 blocks/CU):
//  * 128 x BN tile, BK=128, 512 threads (8 waves, 4x2), single-buffer LDS,
//    two barriers per 128-wide K-tile, 16x16x32 MFMA, c^(r&15) XOR swizzle.
//  * 1D grid of 512, decoded so each XCD (b&7 round-robin) owns an 8x8 patch
//    of the 16x32 block grid (L2 locality). Both GEMM grids are 16x32.
//  * Post-mortem of rounds 1-3: every hand-scheduled pipeline (counted vmcnt,
//    4-phase, 3-ring) LOST vs this structure because they either shrank
//    MFMA-per-barrier or dropped to 1 block/CU; the co-resident second block
//    (m114 wave-overlap) is what hides the __syncthreads vmcnt(0) drain.
//    Do not re-attempt source pipelining without the exact m201 reference.
// ---------------------------------------------------------------------------
template<int BN, bool DUAL>
__global__ __launch_bounds__(512, 4)
void gemm_q8_kernel(const bf16_t* __restrict__ A, const bf16_t* __restrict__ B,
                    float* __restrict__ outf, bf16_t* __restrict__ outb,
                    int M, int N, int K) {
    constexpr int BM = 128;
    constexpr int BK = 128;                        // 16 chunks of 8 elems per row
    constexpr int NI = BN / 32;
    constexpr int A_ITS = BM * (BK / 8) / 512;     // 4
    constexpr int B_ITS = BN * (BK / 8) / 512;     // 4 (BN=128) / 2 (BN=64)

    __shared__ alignas(16) bf16_t sA[BM * BK];
    __shared__ alignas(16) bf16_t sB[BN * BK];

    const int tid  = threadIdx.x;
    const int lane = tid & 63;
    const int wave = tid >> 6;       // 0..7
    const int wm   = wave & 3;       // 4 m-strips of 32 rows
    const int wn   = wave >> 2;      // 2 n-strips of BN/2
    const int ln16 = lane & 15;
    const int quad = lane >> 4;

    // XCD patch swizzle: grid = 512 linear; xcd = b&7 gets 8x8 patch of (x,y)
    const int b   = blockIdx.x;
    const int xcd = b & 7;
    const int g   = b >> 3;                        // 0..63
    const int bx  = (xcd & 1) * 8 + (g & 7);       // 0..15
    const int by  = (xcd >> 1) * 8 + (g >> 3);     // 0..31
    const int brow = by * BM;
    const int bcol = bx * BN;

    // staging: LDS lane-linear slots, global column chunk XOR-permuted
    const bf16_t* gA[A_ITS];
#pragma unroll
    for (int it = 0; it < A_ITS; ++it) {
        int L = it * 512 + tid;
        int r = L >> 4, c = L & 15;
        gA[it] = A + (size_t)(brow + r) * K + (c ^ (r & 15)) * 8;
    }
    const bf16_t* gB[B_ITS];
#pragma unroll
    for (int it = 0; it < B_ITS; ++it) {
        int L = it * 512 + tid;
        int r = L >> 4, c = L & 15;
        gB[it] = B + (size_t)(bcol + r) * K + (c ^ (r & 15)) * 8;
    }

    // loop-invariant fragment LDS offsets (elements), s = K-substep (0..3)
    int a_off[2][4], b_off[NI][4];
#pragma unroll
    for (int im = 0; im < 2; ++im) {
        int r = wm * 32 + im * 16 + ln16;
#pragma unroll
        for (int s = 0; s < 4; ++s) {
            int cg = s * 4 + quad;
            a_off[im][s] = (r * 16 + (cg ^ (r & 15))) * 8;
        }
    }
#pragma unroll
    for (int in = 0; in < NI; ++in) {
        int r = wn * (BN / 2) + in * 16 + ln16;
#pragma unroll
        for (int s = 0; s < 4; ++s) {
            int cg = s * 4 + quad;
            b_off[in][s] = (r * 16 + (cg ^ (r & 15))) * 8;
        }
    }

    f32x4 acc[2][NI];
#pragma unroll
    for (int im = 0; im < 2; ++im)
#pragma unroll
        for (int in = 0; in < NI; ++in)
            acc[im][in] = (f32x4){0.f, 0.f, 0.f, 0.f};

    for (int kt = 0; kt < K; kt += BK) {
#pragma unroll
        for (int it = 0; it < A_ITS; ++it) {
            gload_lds16(gA[it], sA + (it * 512 + wave * 64) * 8);
            gA[it] += BK;
        }
#pragma unroll
        for (int it = 0; it < B_ITS; ++it) {
            gload_lds16(gB[it], sB + (it * 512 + wave * 64) * 8);
            gB[it] += BK;
        }
        __syncthreads();   // drains vmcnt of async LDS stores + barrier
#pragma unroll
        for (int s = 0; s < 4; ++s) {
            bf16x8 af[2], bfv[NI];
#pragma unroll
            for (int im = 0; im < 2; ++im) af[im]  = *(const bf16x8*)(sA + a_off[im][s]);
#pragma unroll
            for (int in = 0; in < NI; ++in) bfv[in] = *(const bf16x8*)(sB + b_off[in][s]);
#pragma unroll
            for (int im = 0; im < 2; ++im)
#pragma unroll
                for (int in = 0; in < NI; ++in)
                    acc[im][in] = __builtin_amdgcn_mfma_f32_16x16x32_bf16(
                        af[im], bfv[in], acc[im][in], 0, 0, 0);
        }
        __syncthreads();
    }

    // epilogue: C/D layout col = lane&15, row = quad*4 + reg
    const int rbase = quad * 4;
#pragma unroll
    for (int im = 0; im < 2; ++im) {
#pragma unroll
        for (int in = 0; in < NI; ++in) {
            int gm = brow + wm * 32 + im * 16 + rbase;
            int gn = bcol + wn * (BN / 2) + in * 16 + ln16;
#pragma unroll
            for (int r = 0; r < 4; ++r) {
                float v = q8(acc[im][in][r]);
                outf[(size_t)(gm + r) * N + gn] = v;
                if (DUAL) outb[(size_t)(gm + r) * N + gn] = (bf16_t)v;
            }
        }
    }
}

// ---------------------------------------------------------------------------
extern "C" void kernel_launch(void* const* d_in, const int* in_sizes, int n_in,
                              void* d_out, int out_size, void* d_ws, size_t ws_size,
                              hipStream_t stream) {
    const float* x = (const float*)d_in[0];   // 4096 x 2048
    const float* u = (const float*)d_in[1];   // 4096 x 1024
    const float* A = (const float*)d_in[2];   // 2048 x 2048
    const float* B = (const float*)d_in[3];   // 2048 x 1024
    const float* C = (const float*)d_in[4];   // 1024 x 2048

    float* outf = (float*)d_out;
    float* xnf  = outf;                                 // 4096 x 2048 f32
    float* yf   = outf + (size_t)4096 * 2048;           // 4096 x 1024 f32

    uint8_t* ws = (uint8_t*)d_ws;
    bf16_t* XU = (bf16_t*)ws;                                            // 24 MB
    bf16_t* AB = (bf16_t*)(ws + (size_t)25165824);                       // 12 MB
    bf16_t* CQ = (bf16_t*)(ws + (size_t)25165824 + 12582912);            //  4 MB
    bf16_t* XN = (bf16_t*)(ws + (size_t)25165824 + 12582912 + 4194304);  // 16 MB

    pack_all<<<dim3(10240), 256, 0, stream>>>(x, u, A, B, C, XU, AB, CQ);

    // x_next = q8([x|u] @ [Aq|Bq]^T): M=4096 N=2048 K=3072; dual f32+bf16 out
    // grid 16x32 = 512, 1D with XCD patch decode
    gemm_q8_kernel<128, true><<<dim3(512), 512, 0, stream>>>(
        XU, AB, xnf, XN, 4096, 2048, 3072);
    // y = q8(x_next @ Cq^T): M=4096 N=1024 K=2048; grid 16x32 = 512
    gemm_q8_kernel<64, false><<<dim3(512), 512, 0, stream>>>(
        XN, CQ, yf, nullptr, 4096, 1024, 2048);
}

// Round 6
// 198.378 us; speedup vs baseline: 1.1638x; 1.0130x over previous
//
#include <hip/hip_runtime.h>
#include <hip/hip_bf16.h>
#include <stdint.h>

typedef __bf16 bf16_t;
typedef __attribute__((ext_vector_type(8))) __bf16 bf16x8;
typedef __attribute__((ext_vector_type(4))) float f32x4;

// ---------------------------------------------------------------------------
// q8: exact re-implementation of reference to_float8.
// ---------------------------------------------------------------------------
__device__ __forceinline__ float q8(float v) {
    float a = __builtin_fabsf(v);
    float z = a + 1e-8f;
    int ei = ((__float_as_int(z) >> 23) & 0xff) - 127;
    ei = ei > 7 ? 7 : (ei < -7 ? -7 : ei);
    float p  = __int_as_float((ei + 127) << 23);
    float ip = __int_as_float((127 - ei) << 23);
    float m  = __builtin_fmaf(a, ip, -1.0f);
    float mq = __builtin_rintf(m * 8.0f) * 0.125f;
    float r  = (1.0f + mq) * p;
    return v < 0.0f ? -r : r;
}

__device__ __forceinline__ void gload_lds16(const bf16_t* g, bf16_t* l) {
    __builtin_amdgcn_global_load_lds(
        (__attribute__((address_space(1))) void*)(g),
        (__attribute__((address_space(3))) void*)(l), 16, 0, 0);
}

__device__ __forceinline__ bf16x8 cvt8(float4 a, float4 b) {
    bf16x8 o = { (bf16_t)a.x, (bf16_t)a.y, (bf16_t)a.z, (bf16_t)a.w,
                 (bf16_t)b.x, (bf16_t)b.y, (bf16_t)b.z, (bf16_t)b.w };
    return o;
}
__device__ __forceinline__ bf16x8 q8x8(float4 a, float4 b) {
    bf16x8 o = { (bf16_t)q8(a.x), (bf16_t)q8(a.y), (bf16_t)q8(a.z), (bf16_t)q8(a.w),
                 (bf16_t)q8(b.x), (bf16_t)q8(b.y), (bf16_t)q8(b.z), (bf16_t)q8(b.w) };
    return o;
}

// ---------------------------------------------------------------------------
// Fused pack kernel, 10240 blocks x 256 threads, 8 elems/thread, 16B stores.
// (verified passing R1-R5)
// ---------------------------------------------------------------------------
__global__ void pack_all(const float* __restrict__ x, const float* __restrict__ u,
                         const float* __restrict__ A, const float* __restrict__ B,
                         const float* __restrict__ C,
                         bf16_t* __restrict__ XU, bf16_t* __restrict__ AB,
                         bf16_t* __restrict__ CQ) {
    const unsigned bid = blockIdx.x;
    const int tid = threadIdx.x;
    if (bid < 4096u) {
        size_t r = bid; int col = tid * 8;
        float4 v0 = *(const float4*)&x[r * 2048 + col];
        float4 v1 = *(const float4*)&x[r * 2048 + col + 4];
        *(bf16x8*)&XU[r * 3072 + col] = cvt8(v0, v1);
    } else if (bid < 6144u) {
        unsigned b = bid - 4096u;
        size_t r = b * 2 + (tid >> 7); int col = (tid & 127) * 8;
        float4 v0 = *(const float4*)&u[r * 1024 + col];
        float4 v1 = *(const float4*)&u[r * 1024 + col + 4];
        *(bf16x8*)&XU[r * 3072 + 2048 + col] = cvt8(v0, v1);
    } else if (bid < 8192u) {
        size_t r = bid - 6144u; int col = tid * 8;
        float4 v0 = *(const float4*)&A[r * 2048 + col];
        float4 v1 = *(const float4*)&A[r * 2048 + col + 4];
        *(bf16x8*)&AB[r * 3072 + col] = q8x8(v0, v1);
    } else if (bid < 9216u) {
        unsigned b = bid - 8192u;
        size_t r = b * 2 + (tid >> 7); int col = (tid & 127) * 8;
        float4 v0 = *(const float4*)&B[r * 1024 + col];
        float4 v1 = *(const float4*)&B[r * 1024 + col + 4];
        *(bf16x8*)&AB[r * 3072 + 2048 + col] = q8x8(v0, v1);
    } else {
        size_t r = bid - 9216u; int col = tid * 8;
        float4 v0 = *(const float4*)&C[r * 2048 + col];
        float4 v1 = *(const float4*)&C[r * 2048 + col + 4];
        *(bf16x8*)&CQ[r * 2048 + col] = q8x8(v0, v1);
    }
}

// ---------------------------------------------------------------------------
// GEMM (B^T): outf[i,j] = q8( sum_k A[i,k]*B[j,k] ), f32 out, optional bf16.
// Round-12: LDS-BANDWIDTH fix. Analysis of R0 (the 57us/36% anchor):
//   per CU per K-tile-128: LDS reads 2blk x 8w x (8KB A + 16KB B) = 384KB
//   + 128KB gload-LDS writes ~= 4600-5700 cy at 85-112 B/cy, vs MFMA 2064 cy.
//   => LDS-BW-bound; MfmaUtil 36% == MFMA-cy/LDS-cy. Conflicts 0 = no
//   conflict overhead, but raw BW caps throughput. Schedule changes (R1-R3)
//   were doomed: none reduced LDS traffic.
// Fix: per-wave 64x64 output (was 32x64) halves LDS bytes/FLOP (31 vs 46
//   B/kFLOP): 256-thread blocks, 4 waves (2M x 2N), tile 128x128, BK=128,
//   single-buffer 64KB LDS -> still 2 blocks/CU (8 waves). R0's EXACT
//   verified schedule (stage; __syncthreads; 4x(ds_read+16 MFMA);
//   __syncthreads), R0's exact swizzle (c^(r&15)), C-layout, and ascending-K
//   accumulation order -> bit-identical outputs.
// gemm2 same template at BN=64 (48KB LDS -> 3 blocks/CU). Both grids 512
//   blocks (32 x 16), R0's verified XCD 8x8-patch decode.
// ---------------------------------------------------------------------------
template<int BN, bool DUAL>
__global__ __launch_bounds__(256, (BN == 128) ? 2 : 3)
void gemm_q8_v6(const bf16_t* __restrict__ A, const bf16_t* __restrict__ B,
                float* __restrict__ outf, bf16_t* __restrict__ outb,
                int N, int K) {
    constexpr int BM = 128;
    constexpr int BK = 128;                          // 16 chunks of 8 elems/row
    constexpr int NI = BN / 32;                      // 4 (BN=128) / 2 (BN=64)
    constexpr int A_ITS = BM * (BK / 8) / 256;       // 8
    constexpr int B_ITS = BN * (BK / 8) / 256;       // 8 / 4

    __shared__ alignas(16) bf16_t sA[BM * BK];
    __shared__ alignas(16) bf16_t sB[BN * BK];

    const int tid  = threadIdx.x;
    const int lane = tid & 63;
    const int wave = tid >> 6;       // 0..3
    const int wm   = wave & 1;       // 2 m-strips of 64 rows
    const int wn   = wave >> 1;      // 2 n-strips of BN/2 cols
    const int ln16 = lane & 15;
    const int quad = lane >> 4;

    // XCD patch swizzle (R0-verified): 512 blocks; xcd=b&7 owns an 8x8 patch
    // of the 16(bx) x 32(by) grid.
    const int b   = blockIdx.x;
    const int xcd = b & 7;
    const int g   = b >> 3;                        // 0..63
    const int bx  = (xcd & 1) * 8 + (g & 7);       // 0..15  (N-tiles)
    const int by  = (xcd >> 1) * 8 + (g >> 3);     // 0..31  (M-tiles)
    const int brow = by * BM;
    const int bcol = bx * BN;

    // staging bases: load it has r = it*16 + (tid>>4), c = tid&15;
    // (r & 15) == tid>>4 independent of it, so one base + it*16*K covers all.
    const int srow = tid >> 4;
    const int scol = ((tid & 15) ^ srow) * 8;
    const bf16_t* gA0 = A + (size_t)(brow + srow) * K + scol;
    const bf16_t* gB0 = B + (size_t)(bcol + srow) * K + scol;

    // fragment LDS offsets (elements), s = K-substep (0..3) — R0 formulas
    int a_off[4][4], b_off[NI][4];
#pragma unroll
    for (int im = 0; im < 4; ++im) {
        int r = wm * 64 + im * 16 + ln16;
#pragma unroll
        for (int s = 0; s < 4; ++s) {
            int cg = s * 4 + quad;
            a_off[im][s] = (r * 16 + (cg ^ (r & 15))) * 8;
        }
    }
#pragma unroll
    for (int in = 0; in < NI; ++in) {
        int r = wn * (BN / 2) + in * 16 + ln16;
#pragma unroll
        for (int s = 0; s < 4; ++s) {
            int cg = s * 4 + quad;
            b_off[in][s] = (r * 16 + (cg ^ (r & 15))) * 8;
        }
    }

    f32x4 acc[4][NI];
#pragma unroll
    for (int im = 0; im < 4; ++im)
#pragma unroll
        for (int in = 0; in < NI; ++in)
            acc[im][in] = (f32x4){0.f, 0.f, 0.f, 0.f};

    for (int kt = 0; kt < K; kt += BK) {
#pragma unroll
        for (int it = 0; it < A_ITS; ++it)
            gload_lds16(gA0 + (size_t)it * 16 * K, sA + it * 2048 + wave * 512);
        gA0 += BK;
#pragma unroll
        for (int it = 0; it < B_ITS; ++it)
            gload_lds16(gB0 + (size_t)it * 16 * K, sB + it * 2048 + wave * 512);
        gB0 += BK;
        __syncthreads();   // drains vmcnt of async LDS stores + barrier
#pragma unroll
        for (int s = 0; s < 4; ++s) {
            bf16x8 af[4], bfv[NI];
#pragma unroll
            for (int im = 0; im < 4; ++im) af[im]  = *(const bf16x8*)(sA + a_off[im][s]);
#pragma unroll
            for (int in = 0; in < NI; ++in) bfv[in] = *(const bf16x8*)(sB + b_off[in][s]);
#pragma unroll
            for (int im = 0; im < 4; ++im)
#pragma unroll
                for (int in = 0; in < NI; ++in)
                    acc[im][in] = __builtin_amdgcn_mfma_f32_16x16x32_bf16(
                        af[im], bfv[in], acc[im][in], 0, 0, 0);
        }
        __syncthreads();
    }

    // epilogue: C/D layout col = lane&15, row = quad*4 + reg
    const int rbase = quad * 4;
#pragma unroll
    for (int im = 0; im < 4; ++im) {
#pragma unroll
        for (int in = 0; in < NI; ++in) {
            int gm = brow + wm * 64 + im * 16 + rbase;
            int gn = bcol + wn * (BN / 2) + in * 16 + ln16;
#pragma unroll
            for (int r = 0; r < 4; ++r) {
                float v = q8(acc[im][in][r]);
                outf[(size_t)(gm + r) * N + gn] = v;
                if (DUAL) outb[(size_t)(gm + r) * N + gn] = (bf16_t)v;
            }
        }
    }
}

// ---------------------------------------------------------------------------
extern "C" void kernel_launch(void* const* d_in, const int* in_sizes, int n_in,
                              void* d_out, int out_size, void* d_ws, size_t ws_size,
                              hipStream_t stream) {
    const float* x = (const float*)d_in[0];   // 4096 x 2048
    const float* u = (const float*)d_in[1];   // 4096 x 1024
    const float* A = (const float*)d_in[2];   // 2048 x 2048
    const float* B = (const float*)d_in[3];   // 2048 x 1024
    const float* C = (const float*)d_in[4];   // 1024 x 2048

    float* outf = (float*)d_out;
    float* xnf  = outf;                                 // 4096 x 2048 f32
    float* yf   = outf + (size_t)4096 * 2048;           // 4096 x 1024 f32

    uint8_t* ws = (uint8_t*)d_ws;
    bf16_t* XU = (bf16_t*)ws;                                            // 24 MB
    bf16_t* AB = (bf16_t*)(ws + (size_t)25165824);                       // 12 MB
    bf16_t* CQ = (bf16_t*)(ws + (size_t)25165824 + 12582912);            //  4 MB
    bf16_t* XN = (bf16_t*)(ws + (size_t)25165824 + 12582912 + 4194304);  // 16 MB

    pack_all<<<dim3(10240), 256, 0, stream>>>(x, u, A, B, C, XU, AB, CQ);

    // x_next = q8([x|u] @ [Aq|Bq]^T): M=4096 N=2048 K=3072; grid 32x16=512
    gemm_q8_v6<128, true><<<dim3(512), 256, 0, stream>>>(
        XU, AB, xnf, XN, 2048, 3072);
    // y = q8(x_next @ Cq^T): M=4096 N=1024 K=2048; grid 32x16=512
    gemm_q8_v6<64, false><<<dim3(512), 256, 0, stream>>>(
        XN, CQ, yf, nullptr, 1024, 2048);
}